// Round 1
// baseline (13805.051 us; speedup 1.0000x reference)
//
#include <hip/hip_runtime.h>
#include <math.h>

// RITS recurrent imputation. B=256, T=100, F=256, H=512.
// Round 1: correctness-first fp32 multi-launch pipeline.
//   - precompute gamma_h [B*T,512] and alpha [B*T,256] with batched tiled GEMMs
//   - 100 steps x 3 stage kernels (x_h+hh / z_h+c_h+c_c / gates+LSTM)
//   - W_ih/W_hh rows packed as r=4*j+g so each thread's 4 N-cols are the
//     i,f,g,o gates of unit j -> LSTM fused into gates-GEMM epilogue.
// Workspace layout (floats), total 22,743,296 floats = ~91 MB.

#define B_ 256
#define T_ 100
#define F_ 256
#define H_ 512
#define BT_ 25600

#define OFF_H     0u           // 131072  h state [B,H]
#define OFF_C     131072u      // 131072  c state [B,H]
#define OFF_NUM   262144u      // 128     loss numerators per t
#define OFF_DEN   262272u      // 128     mask sums per t
#define OFF_XH    262400u      // 65536   x_h [B,F]
#define OFF_XC    327936u      // 65536   x_c [B,F]
#define OFF_CC    393472u      // 65536   c_c [B,F]
#define OFF_HH    459008u      // 524288  h_dec @ W_hh_p.T + bias_p  [B,2048]
#define OFF_BIASP 983296u      // 2048    packed b_ih+b_hh
#define OFF_WIHP  985344u      // 1048576 packed W_ih [2048,512]
#define OFF_WHHP  2033920u     // 1048576 packed W_hh [2048,512]
#define OFF_GH    3082496u     // 13107200 gamma_h [B*T,512]
#define OFF_ALPHA 16189696u    // 6553600  alpha [B*T,256]

__device__ __forceinline__ float sigm(float x) { return 1.0f / (1.0f + expf(-x)); }

__device__ __forceinline__ float block_reduce_sum(float v, float* red) {
    int tid = threadIdx.x;
    red[tid] = v;
    __syncthreads();
    for (int s = 128; s > 0; s >>= 1) {
        if (tid < s) red[tid] += red[tid + s];
        __syncthreads();
    }
    return red[0];
}

// ---------------- init / prep ----------------

__global__ __launch_bounds__(256) void k_init(float* ws) {
    unsigned i = blockIdx.x * 256u + threadIdx.x;
    if (i < 262272u) ws[i] = 0.0f;   // h, c, num
}

__global__ __launch_bounds__(256) void k_prep(const float* __restrict__ W_ih,
                                              const float* __restrict__ W_hh,
                                              const float* __restrict__ b_ih,
                                              const float* __restrict__ b_hh,
                                              float* __restrict__ wihp,
                                              float* __restrict__ whhp,
                                              float* __restrict__ biasp) {
    int r = blockIdx.x;            // packed row 0..2047, r = 4*j + g
    int j = r >> 2, g = r & 3;
    int src = g * 512 + j;         // original row (gate-major)
    for (int k = threadIdx.x; k < 512; k += 256) {
        wihp[(size_t)r * 512 + k] = W_ih[(size_t)src * 512 + k];
        whhp[(size_t)r * 512 + k] = W_hh[(size_t)src * 512 + k];
    }
    if (threadIdx.x == 0) biasp[r] = b_ih[src] + b_hh[src];
}

__global__ __launch_bounds__(256) void k_den(const float* __restrict__ masks, float* __restrict__ den) {
    __shared__ float red[256];
    int t = blockIdx.x;
    float s = 0.0f;
    for (int idx = threadIdx.x; idx < B_ * F_; idx += 256) {
        int b = idx >> 8, f = idx & 255;
        s += masks[((size_t)b * T_ + t) * F_ + f];
    }
    float tot = block_reduce_sum(s, red);
    if (threadIdx.x == 0) den[t] = tot;
}

// ---------------- batched precompute GEMMs ----------------
// gamma_h: [BT,512] = exp(-relu(D @ W_td_h.T + b)),  K=256
__global__ __launch_bounds__(256) void k_gamma_h(const float* __restrict__ deltas,
                                                 const float* __restrict__ W,
                                                 const float* __restrict__ bias,
                                                 float* __restrict__ gh) {
    __shared__ float As[16][65];
    __shared__ float Bs[16][65];
    int tid = threadIdx.x;
    int tx = tid & 15, ty = tid >> 4;
    int mb = blockIdx.x * 64, nb = blockIdx.y * 64;
    int lr = tid >> 2, lk = (tid & 3) * 4;
    float acc[4][4] = {};
    for (int k0 = 0; k0 < 256; k0 += 16) {
        float4 a = *(const float4*)(deltas + (size_t)(mb + lr) * 256 + k0 + lk);
        float4 b = *(const float4*)(W + (size_t)(nb + lr) * 256 + k0 + lk);
        As[lk + 0][lr] = a.x; As[lk + 1][lr] = a.y; As[lk + 2][lr] = a.z; As[lk + 3][lr] = a.w;
        Bs[lk + 0][lr] = b.x; Bs[lk + 1][lr] = b.y; Bs[lk + 2][lr] = b.z; Bs[lk + 3][lr] = b.w;
        __syncthreads();
#pragma unroll
        for (int kk = 0; kk < 16; kk++) {
            float av[4], bv[4];
#pragma unroll
            for (int i = 0; i < 4; i++) av[i] = As[kk][ty * 4 + i];
#pragma unroll
            for (int j = 0; j < 4; j++) bv[j] = Bs[kk][tx * 4 + j];
#pragma unroll
            for (int i = 0; i < 4; i++)
#pragma unroll
                for (int j = 0; j < 4; j++) acc[i][j] = fmaf(av[i], bv[j], acc[i][j]);
        }
        __syncthreads();
    }
#pragma unroll
    for (int i = 0; i < 4; i++) {
        int r = mb + ty * 4 + i;
#pragma unroll
        for (int j = 0; j < 4; j++) {
            int n = nb + tx * 4 + j;
            float v = acc[i][j] + bias[n];
            gh[(size_t)r * 512 + n] = expf(-fmaxf(v, 0.0f));
        }
    }
}

// alpha: [BT,256] = sigmoid(concat(gamma_x, m) @ W_comb.T + b),  K=512
__global__ __launch_bounds__(256) void k_alpha(const float* __restrict__ deltas,
                                               const float* __restrict__ masks,
                                               const float* __restrict__ Wtdx,
                                               const float* __restrict__ btdx,
                                               const float* __restrict__ Wc,
                                               const float* __restrict__ bc,
                                               float* __restrict__ alpha) {
    __shared__ float As[16][65];
    __shared__ float Bs[16][65];
    int tid = threadIdx.x;
    int tx = tid & 15, ty = tid >> 4;
    int mb = blockIdx.x * 64, nb = blockIdx.y * 64;
    int lr = tid >> 2, lk = (tid & 3) * 4;
    float acc[4][4] = {};
    for (int k0 = 0; k0 < 512; k0 += 16) {
        int kg = k0 + lk;
        float4 a;
        if (kg < 256) {
            float4 d4 = *(const float4*)(deltas + (size_t)(mb + lr) * 256 + kg);
            a.x = expf(-fmaxf(d4.x * Wtdx[(size_t)(kg + 0) * 257] + btdx[kg + 0], 0.0f));
            a.y = expf(-fmaxf(d4.y * Wtdx[(size_t)(kg + 1) * 257] + btdx[kg + 1], 0.0f));
            a.z = expf(-fmaxf(d4.z * Wtdx[(size_t)(kg + 2) * 257] + btdx[kg + 2], 0.0f));
            a.w = expf(-fmaxf(d4.w * Wtdx[(size_t)(kg + 3) * 257] + btdx[kg + 3], 0.0f));
        } else {
            a = *(const float4*)(masks + (size_t)(mb + lr) * 256 + (kg - 256));
        }
        float4 b = *(const float4*)(Wc + (size_t)(nb + lr) * 512 + kg);
        As[lk + 0][lr] = a.x; As[lk + 1][lr] = a.y; As[lk + 2][lr] = a.z; As[lk + 3][lr] = a.w;
        Bs[lk + 0][lr] = b.x; Bs[lk + 1][lr] = b.y; Bs[lk + 2][lr] = b.z; Bs[lk + 3][lr] = b.w;
        __syncthreads();
#pragma unroll
        for (int kk = 0; kk < 16; kk++) {
            float av[4], bv[4];
#pragma unroll
            for (int i = 0; i < 4; i++) av[i] = As[kk][ty * 4 + i];
#pragma unroll
            for (int j = 0; j < 4; j++) bv[j] = Bs[kk][tx * 4 + j];
#pragma unroll
            for (int i = 0; i < 4; i++)
#pragma unroll
                for (int j = 0; j < 4; j++) acc[i][j] = fmaf(av[i], bv[j], acc[i][j]);
        }
        __syncthreads();
    }
#pragma unroll
    for (int i = 0; i < 4; i++) {
        int r = mb + ty * 4 + i;
#pragma unroll
        for (int j = 0; j < 4; j++) {
            int n = nb + tx * 4 + j;
            alpha[(size_t)r * 256 + n] = sigm(acc[i][j] + bc[n]);
        }
    }
}

// ---------------- per-step stages ----------------
// Stage A: A = h * gamma_h[t]  (h_dec, [256,512]); N = 2304 = [x_h(256) | hh(2048 packed)]
__global__ __launch_bounds__(256) void k_stageA(int t,
                                                const float* __restrict__ h_buf,
                                                const float* __restrict__ gh,
                                                const float* __restrict__ W_hist,
                                                const float* __restrict__ b_hist,
                                                const float* __restrict__ whhp,
                                                const float* __restrict__ biasp,
                                                const float* __restrict__ values,
                                                const float* __restrict__ masks,
                                                float* __restrict__ xh,
                                                float* __restrict__ xc,
                                                float* __restrict__ hh,
                                                float* __restrict__ num) {
    __shared__ float As[16][65];
    __shared__ float Bs[16][65];
    __shared__ float red[256];
    int tid = threadIdx.x;
    int tx = tid & 15, ty = tid >> 4;
    int mb = blockIdx.x * 64, nb = blockIdx.y * 64;
    int lr = tid >> 2, lk = (tid & 3) * 4;
    float acc[4][4] = {};
    for (int k0 = 0; k0 < 512; k0 += 16) {
        int kg = k0 + lk;
        int row = mb + lr;
        float4 hv = *(const float4*)(h_buf + (size_t)row * 512 + kg);
        float4 gv = *(const float4*)(gh + ((size_t)row * T_ + t) * 512 + kg);
        float4 a = make_float4(hv.x * gv.x, hv.y * gv.y, hv.z * gv.z, hv.w * gv.w);
        int n = nb + lr;
        float4 b;
        if (nb < 256) b = *(const float4*)(W_hist + (size_t)n * 512 + kg);
        else          b = *(const float4*)(whhp + (size_t)(n - 256) * 512 + kg);
        As[lk + 0][lr] = a.x; As[lk + 1][lr] = a.y; As[lk + 2][lr] = a.z; As[lk + 3][lr] = a.w;
        Bs[lk + 0][lr] = b.x; Bs[lk + 1][lr] = b.y; Bs[lk + 2][lr] = b.z; Bs[lk + 3][lr] = b.w;
        __syncthreads();
#pragma unroll
        for (int kk = 0; kk < 16; kk++) {
            float av[4], bv[4];
#pragma unroll
            for (int i = 0; i < 4; i++) av[i] = As[kk][ty * 4 + i];
#pragma unroll
            for (int j = 0; j < 4; j++) bv[j] = Bs[kk][tx * 4 + j];
#pragma unroll
            for (int i = 0; i < 4; i++)
#pragma unroll
                for (int j = 0; j < 4; j++) acc[i][j] = fmaf(av[i], bv[j], acc[i][j]);
        }
        __syncthreads();
    }
    if (nb < 256) {
        float lsum = 0.0f;
#pragma unroll
        for (int i = 0; i < 4; i++) {
            int b = mb + ty * 4 + i;
#pragma unroll
            for (int j = 0; j < 4; j++) {
                int n = nb + tx * 4 + j;
                float v = acc[i][j] + b_hist[n];
                size_t ridx = ((size_t)b * T_ + t) * 256 + n;
                float x = values[ridx], m = masks[ridx];
                xh[(size_t)b * 256 + n] = v;
                xc[(size_t)b * 256 + n] = m * x + (1.0f - m) * v;
                lsum += fabsf(v - x) * m;
            }
        }
        float tot = block_reduce_sum(lsum, red);
        if (tid == 0) atomicAdd(num + t, tot);
    } else {
#pragma unroll
        for (int i = 0; i < 4; i++) {
            int b = mb + ty * 4 + i;
#pragma unroll
            for (int j = 0; j < 4; j++) {
                int n = nb + tx * 4 + j;
                hh[(size_t)b * 2048 + (n - 256)] = acc[i][j] + biasp[n - 256];
            }
        }
    }
}

// Stage B: z_h GEMM (diag-masked W_feat, K=256) + c_h, c_c, imputed, losses
__global__ __launch_bounds__(256) void k_stageB(int t,
                                                const float* __restrict__ xc,
                                                const float* __restrict__ Wf,
                                                const float* __restrict__ bf,
                                                const float* __restrict__ alpha,
                                                const float* __restrict__ xh,
                                                const float* __restrict__ values,
                                                const float* __restrict__ masks,
                                                float* __restrict__ out_imp,
                                                float* __restrict__ cc,
                                                float* __restrict__ num) {
    __shared__ float As[16][65];
    __shared__ float Bs[16][65];
    __shared__ float red[256];
    int tid = threadIdx.x;
    int tx = tid & 15, ty = tid >> 4;
    int mb = blockIdx.x * 64, nb = blockIdx.y * 64;
    int lr = tid >> 2, lk = (tid & 3) * 4;
    float acc[4][4] = {};
    for (int k0 = 0; k0 < 256; k0 += 16) {
        int kg = k0 + lk;
        float4 a = *(const float4*)(xc + (size_t)(mb + lr) * 256 + kg);
        int n = nb + lr;
        float4 b = *(const float4*)(Wf + (size_t)n * 256 + kg);
        if (kg + 0 == n) b.x = 0.0f;
        if (kg + 1 == n) b.y = 0.0f;
        if (kg + 2 == n) b.z = 0.0f;
        if (kg + 3 == n) b.w = 0.0f;
        As[lk + 0][lr] = a.x; As[lk + 1][lr] = a.y; As[lk + 2][lr] = a.z; As[lk + 3][lr] = a.w;
        Bs[lk + 0][lr] = b.x; Bs[lk + 1][lr] = b.y; Bs[lk + 2][lr] = b.z; Bs[lk + 3][lr] = b.w;
        __syncthreads();
#pragma unroll
        for (int kk = 0; kk < 16; kk++) {
            float av[4], bv[4];
#pragma unroll
            for (int i = 0; i < 4; i++) av[i] = As[kk][ty * 4 + i];
#pragma unroll
            for (int j = 0; j < 4; j++) bv[j] = Bs[kk][tx * 4 + j];
#pragma unroll
            for (int i = 0; i < 4; i++)
#pragma unroll
                for (int j = 0; j < 4; j++) acc[i][j] = fmaf(av[i], bv[j], acc[i][j]);
        }
        __syncthreads();
    }
    float lsum = 0.0f;
#pragma unroll
    for (int i = 0; i < 4; i++) {
        int b = mb + ty * 4 + i;
#pragma unroll
        for (int j = 0; j < 4; j++) {
            int n = nb + tx * 4 + j;
            float z = fmaxf(acc[i][j] + bf[n], 0.0f);
            size_t ridx = ((size_t)b * T_ + t) * 256 + n;
            float a_ = alpha[ridx];
            float xhv = xh[(size_t)b * 256 + n];
            float ch = a_ * z + (1.0f - a_) * xhv;
            float x = values[ridx], m = masks[ridx];
            lsum += (fabsf(z - x) + fabsf(ch - x)) * m;
            float ccv = m * x + (1.0f - m) * ch;
            out_imp[ridx] = ccv;              // imputed[:,t,:] == c_c
            cc[(size_t)b * 256 + n] = ccv;
        }
    }
    float tot = block_reduce_sum(lsum, red);
    if (tid == 0) atomicAdd(num + t, tot);
}

// Stage C: gates GEMM (A = [c_c | m], K=512, W = packed W_ih) + hh add + LSTM
__global__ __launch_bounds__(256) void k_stageC(int t,
                                                const float* __restrict__ cc,
                                                const float* __restrict__ masks,
                                                const float* __restrict__ wihp,
                                                const float* __restrict__ hh,
                                                float* __restrict__ c_buf,
                                                float* __restrict__ h_buf) {
    __shared__ float As[16][65];
    __shared__ float Bs[16][65];
    int tid = threadIdx.x;
    int tx = tid & 15, ty = tid >> 4;
    int mb = blockIdx.x * 64, nb = blockIdx.y * 64;
    int lr = tid >> 2, lk = (tid & 3) * 4;
    float acc[4][4] = {};
    for (int k0 = 0; k0 < 512; k0 += 16) {
        int kg = k0 + lk;
        int row = mb + lr;
        float4 a;
        if (kg < 256) a = *(const float4*)(cc + (size_t)row * 256 + kg);
        else          a = *(const float4*)(masks + ((size_t)row * T_ + t) * 256 + (kg - 256));
        float4 b = *(const float4*)(wihp + (size_t)(nb + lr) * 512 + kg);
        As[lk + 0][lr] = a.x; As[lk + 1][lr] = a.y; As[lk + 2][lr] = a.z; As[lk + 3][lr] = a.w;
        Bs[lk + 0][lr] = b.x; Bs[lk + 1][lr] = b.y; Bs[lk + 2][lr] = b.z; Bs[lk + 3][lr] = b.w;
        __syncthreads();
#pragma unroll
        for (int kk = 0; kk < 16; kk++) {
            float av[4], bv[4];
#pragma unroll
            for (int i = 0; i < 4; i++) av[i] = As[kk][ty * 4 + i];
#pragma unroll
            for (int j = 0; j < 4; j++) bv[j] = Bs[kk][tx * 4 + j];
#pragma unroll
            for (int i = 0; i < 4; i++)
#pragma unroll
                for (int j = 0; j < 4; j++) acc[i][j] = fmaf(av[i], bv[j], acc[i][j]);
        }
        __syncthreads();
    }
    // thread's 4 cols = packed gates (i,f,g,o) of unit j
#pragma unroll
    for (int i = 0; i < 4; i++) {
        int b = mb + ty * 4 + i;
        int c0 = nb + tx * 4;
        int j = c0 >> 2;
        float ig = acc[i][0] + hh[(size_t)b * 2048 + c0 + 0];
        float fg = acc[i][1] + hh[(size_t)b * 2048 + c0 + 1];
        float gg = acc[i][2] + hh[(size_t)b * 2048 + c0 + 2];
        float og = acc[i][3] + hh[(size_t)b * 2048 + c0 + 3];
        float cold = c_buf[(size_t)b * 512 + j];
        float cn = sigm(fg) * cold + sigm(ig) * tanhf(gg);
        float hn = sigm(og) * tanhf(cn);
        c_buf[(size_t)b * 512 + j] = cn;
        h_buf[(size_t)b * 512 + j] = hn;
    }
}

// ---------------- finalize ----------------
__global__ __launch_bounds__(256) void k_final(const float* __restrict__ num,
                                               const float* __restrict__ den,
                                               const float* __restrict__ h_buf,
                                               float* __restrict__ out) {
    int tid = threadIdx.x;
    if (blockIdx.x == 0) {
        __shared__ float red[256];
        float v = 0.0f;
        if (tid < T_) v = num[tid] / (den[tid] + 1e-9f);
        red[tid] = v;
        __syncthreads();
        for (int s = 128; s > 0; s >>= 1) {
            if (tid < s) red[tid] += red[tid + s];
            __syncthreads();
        }
        if (tid == 0) out[6684672] = red[0] / 300.0f;   // B*T*F + B*H
    } else {
        int i = (blockIdx.x - 1) * 256 + tid;
        out[6553600 + i] = h_buf[i];                    // final h
    }
}

extern "C" void kernel_launch(void* const* d_in, const int* in_sizes, int n_in,
                              void* d_out, int out_size, void* d_ws, size_t ws_size,
                              hipStream_t stream) {
    (void)in_sizes; (void)n_in; (void)out_size; (void)ws_size;
    const float* values = (const float*)d_in[0];
    const float* masks  = (const float*)d_in[1];
    const float* deltas = (const float*)d_in[2];
    const float* W_td_h = (const float*)d_in[3];
    const float* b_td_h = (const float*)d_in[4];
    const float* W_td_x = (const float*)d_in[5];
    const float* b_td_x = (const float*)d_in[6];
    const float* W_hist = (const float*)d_in[7];
    const float* b_hist = (const float*)d_in[8];
    const float* W_feat = (const float*)d_in[9];
    const float* b_feat = (const float*)d_in[10];
    const float* W_comb = (const float*)d_in[11];
    const float* b_comb = (const float*)d_in[12];
    const float* W_ih   = (const float*)d_in[13];
    const float* W_hh   = (const float*)d_in[14];
    const float* b_ih   = (const float*)d_in[15];
    const float* b_hh   = (const float*)d_in[16];

    float* ws    = (float*)d_ws;
    float* h_buf = ws + OFF_H;
    float* c_buf = ws + OFF_C;
    float* num   = ws + OFF_NUM;
    float* den   = ws + OFF_DEN;
    float* xh    = ws + OFF_XH;
    float* xc    = ws + OFF_XC;
    float* cc    = ws + OFF_CC;
    float* hh    = ws + OFF_HH;
    float* biasp = ws + OFF_BIASP;
    float* wihp  = ws + OFF_WIHP;
    float* whhp  = ws + OFF_WHHP;
    float* gh    = ws + OFF_GH;
    float* alpha = ws + OFF_ALPHA;
    float* out   = (float*)d_out;

    k_init<<<1025, 256, 0, stream>>>(ws);
    k_prep<<<2048, 256, 0, stream>>>(W_ih, W_hh, b_ih, b_hh, wihp, whhp, biasp);
    k_den<<<100, 256, 0, stream>>>(masks, den);
    k_gamma_h<<<dim3(400, 8), 256, 0, stream>>>(deltas, W_td_h, b_td_h, gh);
    k_alpha<<<dim3(400, 4), 256, 0, stream>>>(deltas, masks, W_td_x, b_td_x, W_comb, b_comb, alpha);

    for (int t = 0; t < T_; t++) {
        k_stageA<<<dim3(4, 36), 256, 0, stream>>>(t, h_buf, gh, W_hist, b_hist, whhp, biasp,
                                                  values, masks, xh, xc, hh, num);
        k_stageB<<<dim3(4, 4), 256, 0, stream>>>(t, xc, W_feat, b_feat, alpha, xh,
                                                 values, masks, out, cc, num);
        k_stageC<<<dim3(4, 32), 256, 0, stream>>>(t, cc, masks, wihp, hh, c_buf, h_buf);
    }
    k_final<<<513, 256, 0, stream>>>(num, den, h_buf, out);
}

// Round 2
// 10217.226 us; speedup vs baseline: 1.3512x; 1.3512x over previous
//
#include <hip/hip_runtime.h>
#include <math.h>

// RITS recurrent imputation. B=256, T=100, F=256, H=512.
// Round 2: single persistent kernel for the T-loop (custom device-scope grid
// sync), bf16 MFMA (16x16x32) with LDS-resident weight slices.
//   phase A (wgs 0-63):  x_h = hdec @ W_hist.T            [256x256, K=512]
//   phase B (wgs 0-63):  z_h = x_c @ Wf.T + epilogue      [256x256, K=256]
//   phase C (all 256):   gates = [cc|m|hdec] @ [Wih|Whh].T [256x2048, K=1024]
//                        + fused LSTM update (packed gate rows n=4j+g)
// hdec double-buffered by t parity (phase C reads old, writes new).

#define T_ 100

typedef unsigned short ushortT;
typedef __attribute__((ext_vector_type(8))) short short8;
typedef __attribute__((ext_vector_type(4))) float f32x4;

// ---- workspace byte offsets ----
#define OB_H      0u          // fp32 h [256*512]
#define OB_C      524288u     // fp32 c
#define OB_HD0    1048576u    // bf16 hdec buf0 [256*512]
#define OB_HD1    1310720u    // bf16 hdec buf1
#define OB_XH     1572864u    // fp32 x_h [256*256]
#define OB_XCB    1835008u    // bf16 x_c
#define OB_CCB    1966080u    // bf16 c_c
#define OB_NUM2   2097152u    // fp32 [100*64] loss partials
#define OB_DEN    2122752u    // fp32 [128]
#define OB_CNT    2123264u    // u32 sync counter
#define OB_BIASP  2123776u    // fp32 [2048] packed b_ih+b_hh
#define OB_BA     2131968u    // bf16 W_hist [256*512]
#define OB_BB     2394112u    // bf16 Wf masked [256*256]
#define OB_BC     2525184u    // bf16 packed [2048*1024] = [wihp|whhp]
#define OB_MT     6719488u    // bf16 masks time-major [100*256*256]
#define OB_GH     19826688u   // bf16 gamma_h [25600*512]
#define OB_AL     46041088u   // bf16 alpha [25600*256]
// end 59,148,288 B (~56.4 MB) < ws_size (>= 91 MB from round 1)

__device__ __forceinline__ float sigm(float x) { return 1.0f / (1.0f + expf(-x)); }

__device__ __forceinline__ ushortT f2bf(float f) {
    union { float f; unsigned u; } v; v.f = f;
    unsigned r = v.u + 0x7fffu + ((v.u >> 16) & 1u);   // RNE
    return (ushortT)(r >> 16);
}
__device__ __forceinline__ float bf2f(ushortT h) {
    union { unsigned u; float f; } v; v.u = ((unsigned)h) << 16; return v.f;
}

__device__ __forceinline__ void gsync(unsigned* cnt, unsigned epoch) {
    __syncthreads();
    if (threadIdx.x == 0) {
        __threadfence();   // release: writeback local L2 (cross-XCD visibility)
        __hip_atomic_fetch_add(cnt, 1u, __ATOMIC_RELEASE, __HIP_MEMORY_SCOPE_AGENT);
        unsigned want = epoch * 256u;
        while (__hip_atomic_load(cnt, __ATOMIC_ACQUIRE, __HIP_MEMORY_SCOPE_AGENT) < want)
            __builtin_amdgcn_s_sleep(2);
        __threadfence();   // acquire: invalidate stale lines
    }
    __syncthreads();
}

// ---------------- prep kernels ----------------

__global__ __launch_bounds__(256) void k_init2(unsigned char* wsb) {
    unsigned i = blockIdx.x * 256u + threadIdx.x;   // 1280 blocks: 327,680 words
    unsigned* w = (unsigned*)wsb;
    if (i < 327680u) w[i] = 0u;                     // h, c, hdec buf0
    if (i == 0) *(unsigned*)(wsb + OB_CNT) = 0u;
}

__global__ __launch_bounds__(256) void k_prep2(const float* __restrict__ W_ih,
                                               const float* __restrict__ W_hh,
                                               const float* __restrict__ b_ih,
                                               const float* __restrict__ b_hh,
                                               const float* __restrict__ W_hist,
                                               const float* __restrict__ W_feat,
                                               unsigned char* wsb) {
    ushortT* Bc = (ushortT*)(wsb + OB_BC);
    ushortT* Ba = (ushortT*)(wsb + OB_BA);
    ushortT* Bb = (ushortT*)(wsb + OB_BB);
    float* biasp = (float*)(wsb + OB_BIASP);
    int n = blockIdx.x;                  // packed row, n = 4*j + g
    int j = n >> 2, g = n & 3;
    int src = g * 512 + j;
    for (int k = threadIdx.x; k < 512; k += 256) {
        Bc[(size_t)n * 1024 + k]       = f2bf(W_ih[(size_t)src * 512 + k]);
        Bc[(size_t)n * 1024 + 512 + k] = f2bf(W_hh[(size_t)src * 512 + k]);
        if (n < 256) {
            Ba[(size_t)n * 512 + k] = f2bf(W_hist[(size_t)n * 512 + k]);
            if (k < 256) Bb[(size_t)n * 256 + k] = (k == n) ? 0 : f2bf(W_feat[(size_t)n * 256 + k]);
        }
    }
    if (threadIdx.x == 0) biasp[n] = b_ih[src] + b_hh[src];
}

__global__ __launch_bounds__(256) void k_den(const float* __restrict__ masks, unsigned char* wsb) {
    __shared__ float red[256];
    float* den = (float*)(wsb + OB_DEN);
    int t = blockIdx.x;
    float s = 0.0f;
    for (int idx = threadIdx.x; idx < 256 * 256; idx += 256) {
        int b = idx >> 8, f = idx & 255;
        s += masks[((size_t)b * T_ + t) * 256 + f];
    }
    red[threadIdx.x] = s; __syncthreads();
    for (int st = 128; st > 0; st >>= 1) { if (threadIdx.x < st) red[threadIdx.x] += red[threadIdx.x + st]; __syncthreads(); }
    if (threadIdx.x == 0) den[t] = red[0];
}

__global__ __launch_bounds__(256) void k_maskt(const float* __restrict__ masks, unsigned char* wsb) {
    ushortT* mt = (ushortT*)(wsb + OB_MT);
    unsigned gidx = blockIdx.x * 256u + threadIdx.x;   // 6400 blocks -> 1,638,400
    int f4 = gidx & 63;
    unsigned rest = gidx >> 6;                          // 0..25599
    int t = rest % 100, b = rest / 100;
    float4 m = *(const float4*)(masks + ((size_t)b * T_ + t) * 256 + f4 * 4);
    size_t o = ((size_t)t * 256 + b) * 256 + f4 * 4;
    mt[o + 0] = f2bf(m.x); mt[o + 1] = f2bf(m.y); mt[o + 2] = f2bf(m.z); mt[o + 3] = f2bf(m.w);
}

// gamma_h: [25600,512] = exp(-relu(D @ W_td_h.T + b)), K=256 (fp32 tile GEMM)
__global__ __launch_bounds__(256) void k_gamma_h(const float* __restrict__ deltas,
                                                 const float* __restrict__ W,
                                                 const float* __restrict__ bias,
                                                 unsigned char* wsb) {
    ushortT* gh = (ushortT*)(wsb + OB_GH);
    __shared__ float As[16][65];
    __shared__ float Bs[16][65];
    int tid = threadIdx.x;
    int tx = tid & 15, ty = tid >> 4;
    int mb = blockIdx.x * 64, nb = blockIdx.y * 64;
    int lr = tid >> 2, lk = (tid & 3) * 4;
    float acc[4][4] = {};
    for (int k0 = 0; k0 < 256; k0 += 16) {
        float4 a = *(const float4*)(deltas + (size_t)(mb + lr) * 256 + k0 + lk);
        float4 b = *(const float4*)(W + (size_t)(nb + lr) * 256 + k0 + lk);
        As[lk + 0][lr] = a.x; As[lk + 1][lr] = a.y; As[lk + 2][lr] = a.z; As[lk + 3][lr] = a.w;
        Bs[lk + 0][lr] = b.x; Bs[lk + 1][lr] = b.y; Bs[lk + 2][lr] = b.z; Bs[lk + 3][lr] = b.w;
        __syncthreads();
#pragma unroll
        for (int kk = 0; kk < 16; kk++) {
            float av[4], bv[4];
#pragma unroll
            for (int i = 0; i < 4; i++) av[i] = As[kk][ty * 4 + i];
#pragma unroll
            for (int j = 0; j < 4; j++) bv[j] = Bs[kk][tx * 4 + j];
#pragma unroll
            for (int i = 0; i < 4; i++)
#pragma unroll
                for (int j = 0; j < 4; j++) acc[i][j] = fmaf(av[i], bv[j], acc[i][j]);
        }
        __syncthreads();
    }
#pragma unroll
    for (int i = 0; i < 4; i++) {
        int r = mb + ty * 4 + i;
#pragma unroll
        for (int j = 0; j < 4; j++) {
            int n = nb + tx * 4 + j;
            float v = acc[i][j] + bias[n];
            gh[(size_t)r * 512 + n] = f2bf(expf(-fmaxf(v, 0.0f)));
        }
    }
}

// alpha: [25600,256] = sigmoid([gamma_x|m] @ W_comb.T + b), K=512
__global__ __launch_bounds__(256) void k_alpha(const float* __restrict__ deltas,
                                               const float* __restrict__ masks,
                                               const float* __restrict__ Wtdx,
                                               const float* __restrict__ btdx,
                                               const float* __restrict__ Wc,
                                               const float* __restrict__ bc,
                                               unsigned char* wsb) {
    ushortT* al = (ushortT*)(wsb + OB_AL);
    __shared__ float As[16][65];
    __shared__ float Bs[16][65];
    int tid = threadIdx.x;
    int tx = tid & 15, ty = tid >> 4;
    int mb = blockIdx.x * 64, nb = blockIdx.y * 64;
    int lr = tid >> 2, lk = (tid & 3) * 4;
    float acc[4][4] = {};
    for (int k0 = 0; k0 < 512; k0 += 16) {
        int kg = k0 + lk;
        float4 a;
        if (kg < 256) {
            float4 d4 = *(const float4*)(deltas + (size_t)(mb + lr) * 256 + kg);
            a.x = expf(-fmaxf(d4.x * Wtdx[(size_t)(kg + 0) * 257] + btdx[kg + 0], 0.0f));
            a.y = expf(-fmaxf(d4.y * Wtdx[(size_t)(kg + 1) * 257] + btdx[kg + 1], 0.0f));
            a.z = expf(-fmaxf(d4.z * Wtdx[(size_t)(kg + 2) * 257] + btdx[kg + 2], 0.0f));
            a.w = expf(-fmaxf(d4.w * Wtdx[(size_t)(kg + 3) * 257] + btdx[kg + 3], 0.0f));
        } else {
            a = *(const float4*)(masks + (size_t)(mb + lr) * 256 + (kg - 256));
        }
        float4 b = *(const float4*)(Wc + (size_t)(nb + lr) * 512 + kg);
        As[lk + 0][lr] = a.x; As[lk + 1][lr] = a.y; As[lk + 2][lr] = a.z; As[lk + 3][lr] = a.w;
        Bs[lk + 0][lr] = b.x; Bs[lk + 1][lr] = b.y; Bs[lk + 2][lr] = b.z; Bs[lk + 3][lr] = b.w;
        __syncthreads();
#pragma unroll
        for (int kk = 0; kk < 16; kk++) {
            float av[4], bv[4];
#pragma unroll
            for (int i = 0; i < 4; i++) av[i] = As[kk][ty * 4 + i];
#pragma unroll
            for (int j = 0; j < 4; j++) bv[j] = Bs[kk][tx * 4 + j];
#pragma unroll
            for (int i = 0; i < 4; i++)
#pragma unroll
                for (int j = 0; j < 4; j++) acc[i][j] = fmaf(av[i], bv[j], acc[i][j]);
        }
        __syncthreads();
    }
#pragma unroll
    for (int i = 0; i < 4; i++) {
        int r = mb + ty * 4 + i;
#pragma unroll
        for (int j = 0; j < 4; j++) {
            int n = nb + tx * 4 + j;
            al[(size_t)r * 256 + n] = f2bf(sigm(acc[i][j] + bc[n]));
        }
    }
}

// ---------------- persistent kernel ----------------

__global__ __launch_bounds__(256, 1) void k_persist(const float* __restrict__ values,
                                                    const float* __restrict__ masks,
                                                    const float* __restrict__ b_hist,
                                                    const float* __restrict__ b_feat,
                                                    float* __restrict__ out,
                                                    unsigned char* __restrict__ wsb) {
    float* h_buf = (float*)(wsb + OB_H);
    float* c_buf = (float*)(wsb + OB_C);
    ushortT* hd[2] = { (ushortT*)(wsb + OB_HD0), (ushortT*)(wsb + OB_HD1) };
    float* xh = (float*)(wsb + OB_XH);
    ushortT* xcb = (ushortT*)(wsb + OB_XCB);
    ushortT* ccb = (ushortT*)(wsb + OB_CCB);
    float* num2 = (float*)(wsb + OB_NUM2);
    const float* den = (const float*)(wsb + OB_DEN);
    unsigned* cnt = (unsigned*)(wsb + OB_CNT);
    const float* biasp = (const float*)(wsb + OB_BIASP);
    const ushortT* Ba = (const ushortT*)(wsb + OB_BA);
    const ushortT* Bb = (const ushortT*)(wsb + OB_BB);
    const ushortT* Bc = (const ushortT*)(wsb + OB_BC);
    const ushortT* mt = (const ushortT*)(wsb + OB_MT);
    const ushortT* gh = (const ushortT*)(wsb + OB_GH);
    const ushortT* al = (const ushortT*)(wsb + OB_AL);

    __shared__ ushortT ldsBc[16 * 1032];   // 33024 B, +8 pad breaks bank conflicts
    __shared__ ushortT ldsBa[16 * 520];    // 16640 B
    __shared__ ushortT ldsBb[16 * 264];    //  8448 B
    __shared__ float scr[4 * 256];         //  4096 B
    __shared__ float lossSlots[8];

    const int wg = blockIdx.x, tid = threadIdx.x;
    const int wave = tid >> 6, lane = tid & 63, quad = lane >> 4, l16 = lane & 15;

    // ---- load LDS weight slices (once) ----
    {
        int n0 = (wg & 127) * 16;
        for (int i = tid; i < 2048; i += 256) {       // 16 rows x 128 chunks of 8
            int r = i >> 7, c = i & 127;
            *(short8*)&ldsBc[r * 1032 + c * 8] = *(const short8*)&Bc[(size_t)(n0 + r) * 1024 + c * 8];
        }
        if (wg < 64) {
            int nA = (wg & 15) * 16;
            for (int i = tid; i < 1024; i += 256) {   // 16 x 64
                int r = i >> 6, c = i & 63;
                *(short8*)&ldsBa[r * 520 + c * 8] = *(const short8*)&Ba[(size_t)(nA + r) * 512 + c * 8];
            }
            for (int i = tid; i < 512; i += 256) {    // 16 x 32
                int r = i >> 5, c = i & 31;
                *(short8*)&ldsBb[r * 264 + c * 8] = *(const short8*)&Bb[(size_t)(nA + r) * 256 + c * 8];
            }
        }
        __syncthreads();
    }

    unsigned epoch = 0;
    for (int t = 0; t < T_; ++t) {
        const ushortT* hdA = hd[t & 1];
        ushortT* hdW = hd[(t + 1) & 1];

        // ---- phase A: x_h = hdec @ W_hist.T ----
        if (wg < 64) {
            int mb = (wg >> 4) * 64, nb = (wg & 15) * 16;
            int rowA = mb + wave * 16;
            f32x4 acc = {0.f, 0.f, 0.f, 0.f};
            const ushortT* aBase = hdA + (size_t)(rowA + l16) * 512 + quad * 8;
#pragma unroll 4
            for (int kc = 0; kc < 16; ++kc) {
                short8 a = *(const short8*)(aBase + kc * 32);
                short8 b = *(const short8*)&ldsBa[l16 * 520 + kc * 32 + quad * 8];
                acc = __builtin_amdgcn_mfma_f32_16x16x32_bf16(a, b, acc, 0, 0, 0);
            }
            int n = nb + l16;
            float bh = b_hist[n];
            float ls = 0.f;
#pragma unroll
            for (int r4 = 0; r4 < 4; ++r4) {
                int r = rowA + quad * 4 + r4;
                float v = acc[r4] + bh;
                size_t idx = ((size_t)r * T_ + t) * 256 + n;
                float x = values[idx], m = masks[idx];
                xh[r * 256 + n] = v;
                xcb[r * 256 + n] = f2bf(m * x + (1.f - m) * v);
                ls += fabsf(v - x) * m;
            }
            for (int off = 32; off; off >>= 1) ls += __shfl_down(ls, off);
            if (lane == 0) lossSlots[wave] = ls;
        }
        gsync(cnt, ++epoch);

        // ---- phase B: z_h = x_c @ Wf.T; c_h, c_c, losses ----
        if (wg < 64) {
            int mb = (wg >> 4) * 64, nb = (wg & 15) * 16;
            int rowA = mb + wave * 16;
            f32x4 acc = {0.f, 0.f, 0.f, 0.f};
            const ushortT* aBase = xcb + (size_t)(rowA + l16) * 256 + quad * 8;
#pragma unroll 4
            for (int kc = 0; kc < 8; ++kc) {
                short8 a = *(const short8*)(aBase + kc * 32);
                short8 b = *(const short8*)&ldsBb[l16 * 264 + kc * 32 + quad * 8];
                acc = __builtin_amdgcn_mfma_f32_16x16x32_bf16(a, b, acc, 0, 0, 0);
            }
            int n = nb + l16;
            float bfv = b_feat[n];
            float ls = 0.f;
#pragma unroll
            for (int r4 = 0; r4 < 4; ++r4) {
                int r = rowA + quad * 4 + r4;
                float z = fmaxf(acc[r4] + bfv, 0.f);
                size_t idx = ((size_t)r * T_ + t) * 256 + n;
                float a_ = bf2f(al[idx]);
                float xhv = xh[r * 256 + n];
                float ch = a_ * z + (1.f - a_) * xhv;
                float x = values[idx], m = masks[idx];
                float ccv = m * x + (1.f - m) * ch;
                out[idx] = ccv;                       // imputed[:,t,:] == c_c
                ccb[r * 256 + n] = f2bf(ccv);
                ls += (fabsf(z - x) + fabsf(ch - x)) * m;
            }
            for (int off = 32; off; off >>= 1) ls += __shfl_down(ls, off);
            if (lane == 0) lossSlots[4 + wave] = ls;
            __syncthreads();
            if (tid == 0) {
                float s = 0.f;
                for (int i = 0; i < 8; ++i) s += lossSlots[i];
                num2[t * 64 + wg] = s;
            }
        }
        gsync(cnt, ++epoch);

        // ---- phase C: gates = [cc|m|hdec] @ BcT (K=1024) + LSTM ----
        {
            int mb = (wg >> 7) * 128, nb = (wg & 127) * 16;
            int r0 = mb + wave * 32;
            f32x4 acc0 = {0.f, 0.f, 0.f, 0.f}, acc1 = {0.f, 0.f, 0.f, 0.f};
            const ushortT* mtT = mt + (size_t)t * 65536;
            {
                const ushortT* a0p = ccb + (size_t)(r0 + l16) * 256 + quad * 8;
                const ushortT* a1p = a0p + 16 * 256;
#pragma unroll 4
                for (int kc = 0; kc < 8; ++kc) {
                    short8 a0 = *(const short8*)(a0p + kc * 32);
                    short8 a1 = *(const short8*)(a1p + kc * 32);
                    short8 b = *(const short8*)&ldsBc[l16 * 1032 + kc * 32 + quad * 8];
                    acc0 = __builtin_amdgcn_mfma_f32_16x16x32_bf16(a0, b, acc0, 0, 0, 0);
                    acc1 = __builtin_amdgcn_mfma_f32_16x16x32_bf16(a1, b, acc1, 0, 0, 0);
                }
            }
            {
                const ushortT* a0p = mtT + (size_t)(r0 + l16) * 256 + quad * 8;
                const ushortT* a1p = a0p + 16 * 256;
#pragma unroll 4
                for (int kc = 0; kc < 8; ++kc) {
                    short8 a0 = *(const short8*)(a0p + kc * 32);
                    short8 a1 = *(const short8*)(a1p + kc * 32);
                    short8 b = *(const short8*)&ldsBc[l16 * 1032 + 256 + kc * 32 + quad * 8];
                    acc0 = __builtin_amdgcn_mfma_f32_16x16x32_bf16(a0, b, acc0, 0, 0, 0);
                    acc1 = __builtin_amdgcn_mfma_f32_16x16x32_bf16(a1, b, acc1, 0, 0, 0);
                }
            }
            {
                const ushortT* a0p = hdA + (size_t)(r0 + l16) * 512 + quad * 8;
                const ushortT* a1p = a0p + 16 * 512;
#pragma unroll 4
                for (int kc = 0; kc < 16; ++kc) {
                    short8 a0 = *(const short8*)(a0p + kc * 32);
                    short8 a1 = *(const short8*)(a1p + kc * 32);
                    short8 b = *(const short8*)&ldsBc[l16 * 1032 + 512 + kc * 32 + quad * 8];
                    acc0 = __builtin_amdgcn_mfma_f32_16x16x32_bf16(a0, b, acc0, 0, 0, 0);
                    acc1 = __builtin_amdgcn_mfma_f32_16x16x32_bf16(a1, b, acc1, 0, 0, 0);
                }
            }
            float bp = biasp[nb + l16];
            float* ms = scr + wave * 256;
#pragma unroll
            for (int tt = 0; tt < 2; ++tt) {
                __syncthreads();                       // scr reuse fence
                int Mb = r0 + tt * 16;
#pragma unroll
                for (int r4 = 0; r4 < 4; ++r4) {
                    float g = (tt ? acc1[r4] : acc0[r4]) + bp;
                    ms[(quad * 4 + r4) * 16 + l16] = g;
                }
                __syncthreads();                       // writes visible
                int rloc = lane >> 2, u = lane & 3;
                float gi = ms[rloc * 16 + u * 4 + 0];
                float gf = ms[rloc * 16 + u * 4 + 1];
                float gg = ms[rloc * 16 + u * 4 + 2];
                float go = ms[rloc * 16 + u * 4 + 3];
                int b = Mb + rloc;
                int j = (nb >> 2) + u;
                float cold = c_buf[(size_t)b * 512 + j];
                float cn = sigm(gf) * cold + sigm(gi) * tanhf(gg);
                float hn = sigm(go) * tanhf(cn);
                c_buf[(size_t)b * 512 + j] = cn;
                h_buf[(size_t)b * 512 + j] = hn;
                float gv = 0.f;
                if (t < T_ - 1) gv = bf2f(gh[((size_t)b * T_ + t + 1) * 512 + j]);
                hdW[(size_t)b * 512 + j] = f2bf(hn * gv);
            }
        }
        gsync(cnt, ++epoch);
    }

    // ---- finalize ----
    if (wg == 0) {
        float v = 0.f;
        if (tid < T_) {
            float s = 0.f;
            for (int w = 0; w < 64; ++w) s += num2[tid * 64 + w];
            v = s / (den[tid] + 1e-9f);
        }
        scr[tid] = v;
        __syncthreads();
        for (int s = 128; s > 0; s >>= 1) { if (tid < s) scr[tid] += scr[tid + s]; __syncthreads(); }
        if (tid == 0) out[6684672] = scr[0] / 300.0f;
    }
    ((float2*)(out + 6553600))[wg * 256 + tid] = ((const float2*)h_buf)[wg * 256 + tid];
}

extern "C" void kernel_launch(void* const* d_in, const int* in_sizes, int n_in,
                              void* d_out, int out_size, void* d_ws, size_t ws_size,
                              hipStream_t stream) {
    (void)in_sizes; (void)n_in; (void)out_size; (void)ws_size;
    const float* values = (const float*)d_in[0];
    const float* masks  = (const float*)d_in[1];
    const float* deltas = (const float*)d_in[2];
    const float* W_td_h = (const float*)d_in[3];
    const float* b_td_h = (const float*)d_in[4];
    const float* W_td_x = (const float*)d_in[5];
    const float* b_td_x = (const float*)d_in[6];
    const float* W_hist = (const float*)d_in[7];
    const float* b_hist = (const float*)d_in[8];
    const float* W_feat = (const float*)d_in[9];
    const float* b_feat = (const float*)d_in[10];
    const float* W_comb = (const float*)d_in[11];
    const float* b_comb = (const float*)d_in[12];
    const float* W_ih   = (const float*)d_in[13];
    const float* W_hh   = (const float*)d_in[14];
    const float* b_ih   = (const float*)d_in[15];
    const float* b_hh   = (const float*)d_in[16];

    unsigned char* wsb = (unsigned char*)d_ws;
    float* out = (float*)d_out;

    k_init2<<<1280, 256, 0, stream>>>(wsb);
    k_prep2<<<2048, 256, 0, stream>>>(W_ih, W_hh, b_ih, b_hh, W_hist, W_feat, wsb);
    k_den<<<100, 256, 0, stream>>>(masks, wsb);
    k_maskt<<<6400, 256, 0, stream>>>(masks, wsb);
    k_gamma_h<<<dim3(400, 8), 256, 0, stream>>>(deltas, W_td_h, b_td_h, wsb);
    k_alpha<<<dim3(400, 4), 256, 0, stream>>>(deltas, masks, W_td_x, b_td_x, W_comb, b_comb, wsb);
    k_persist<<<256, 256, 0, stream>>>(values, masks, b_hist, b_feat, out, wsb);
}